// Round 1
// baseline (63.599 us; speedup 1.0000x reference)
//
#include <hip/hip_runtime.h>

// Analytic collapse of the "quantum conv" model:
//   After RY encoding + CNOT chain, qubit w's bit is the XOR of independent
//   Bernoulli(sin^2(x_j/2)) bits j<=w  ->  <Z_w> = prod_{j<=w} cos(x_j).
//   RZ(patch_params) are diagonal phases; |amp|^2 removes them entirely.
//   out[b] = sigmoid(cos( sum_p sum_w feats[b,4p+w] * W[4p+w] ))
//   per-patch Horner: c0*(W0 + c1*(W1 + c2*(W2 + c3*W3))).
// Patch p=(gi,gj), 14x14 grid of 2x2 patches, pixels row-major:
//   offsets base, base+1, base+28, base+29, base = 56*gi + 2*gj.
//
// R5 restructure: one 256-thread block per image (was: one wave per image).
//   - 4x the wave count (16384 waves) for latency hiding; per-thread chain
//     shrinks from 16 scattered dword loads to 2 aligned float2 loads
//     (byte addr = 8*(28*gi+gj) -> 8B-aligned, fully coalesced) plus one
//     float4 weight load (L2-resident, shared across all blocks).
//   - wave shfl reduce -> LDS[4] -> wave-0 finish.
// Output stays FLOAT32 (comparator's "(bf16)" label is the tolerance mode,
// not the buffer dtype — established R2-R4 of the previous session).

#define NPATCH 196
#define IMG    784

__global__ __launch_bounds__(256) void fraud_kernel(
    const float* __restrict__ x,      // [B, 784] f32
    const float* __restrict__ cp,     // [785]    f32
    float* __restrict__ out,          // [B] f32
    int B)
{
    __shared__ float red[4];
    const int tid  = threadIdx.x;
    const int wave = tid >> 6;
    const int lane = tid & 63;

    for (int b = blockIdx.x; b < B; b += gridDim.x) {
        const float* xb = x + (size_t)b * IMG;

        float acc = 0.f;
        if (tid < NPATCH) {
            const int gi   = tid / 14;
            const int gj   = tid - gi * 14;
            const int base = gi * 56 + gj * 2;          // even -> 8B aligned
            const float2 top = *reinterpret_cast<const float2*>(xb + base);
            const float2 bot = *reinterpret_cast<const float2*>(xb + base + 28);
            const float4 w   = *reinterpret_cast<const float4*>(cp + 4 * tid);
            const float c0 = __cosf(top.x);
            const float c1 = __cosf(top.y);
            const float c2 = __cosf(bot.x);
            const float c3 = __cosf(bot.y);
            acc = c0 * fmaf(c1, fmaf(c2, fmaf(c3, w.w, w.z), w.y), w.x);
        }

        // wave64 reduction to lane 0
        #pragma unroll
        for (int off = 32; off > 0; off >>= 1)
            acc += __shfl_down(acc, off, 64);

        if (lane == 0) red[wave] = acc;
        __syncthreads();

        if (tid == 0) {
            const float s = red[0] + red[1] + red[2] + red[3];
            const float c = cosf(s);                   // |s| up to ~60: full range reduction
            out[b] = 1.f / (1.f + __expf(-c));         // sigmoid, stored as f32
        }
        __syncthreads();                               // safe LDS reuse if grid-striding
    }
}

extern "C" void kernel_launch(void* const* d_in, const int* in_sizes, int n_in,
                              void* d_out, int out_size, void* d_ws, size_t ws_size,
                              hipStream_t stream) {
    const float* x  = (const float*)d_in[0];   // [B,1,28,28] f32
    // d_in[1] = patch_params: provably unused (RZ phases cancel in |amp|^2)
    const float* cp = (const float*)d_in[2];   // [785] f32
    float* out = (float*)d_out;                // f32 [B]

    const int B = out_size;                    // elements == batch (4096)
    int blocks = B;                            // one block per image
    if (blocks > 16384) blocks = 16384;
    if (blocks < 1) blocks = 1;
    fraud_kernel<<<blocks, 256, 0, stream>>>(x, cp, out, B);
}